// Round 7
// baseline (1678.087 us; speedup 1.0000x reference)
//
#include <hip/hip_runtime.h>
#include <hip/hip_bf16.h>

// LinearFLH: out[m,n] = sx[m]*sw[n]*(x[m,:].w[n,:]) + bias[n]
// M=8192, N=11008, K=4096.
// RESOLVED (R6 diagnostic): ALL tensors are delivered as FLOAT32 buffers.
// The reference dtype is fp16; the harness cast rule enumerates only
// {bfloat16, float32, integer} -> fp16 falls to float32 for BOTH inputs and
// output. Six rounds of overflow-class garbage came from reading f32 buffers
// as 16-bit halfwords (random mantissa bits -> bf16 exponents up to 2^127).
// Structure: m97 128x128/BK=64 bf16-MFMA GEMM, reg-staged LDS with inline
// f32->bf16 RNE conversion in the staging path. f32 epilogue.

#define M_DIM 8192
#define N_DIM 11008
#define K_DIM 4096
#define BM 128
#define BN 128
#define BK 64

typedef __bf16 bf16x8 __attribute__((ext_vector_type(8)));   // MFMA A/B operand
typedef float f32x4 __attribute__((ext_vector_type(4)));
typedef unsigned short u16x4 __attribute__((ext_vector_type(4)));

// f32 -> bf16 bits, round-to-nearest-even (branchless; inputs are finite)
__device__ __forceinline__ unsigned short f2bf(float f) {
    union { float f; unsigned int u; } c; c.f = f;
    unsigned int r = c.u + 0x7FFFu + ((c.u >> 16) & 1u);
    return (unsigned short)(r >> 16);
}

__global__ __launch_bounds__(256) void linear_flh_kernel(
    const float* __restrict__ X,     // [M, K] f32 (fp16-valued)
    const float* __restrict__ SX,    // [M] f32
    const float* __restrict__ W,     // [N, K] f32
    const float* __restrict__ SW,    // [N] f32
    const float* __restrict__ BIAS,  // [N] f32
    float* __restrict__ OUT)         // [M, N] f32
{
    __shared__ alignas(16) unsigned short smA[BM * BK];   // 16 KiB bf16 bits
    __shared__ alignas(16) unsigned short smB[BN * BK];   // 16 KiB

    const int t = threadIdx.x;          // 0..255
    const int lane = t & 63;
    const int wave = t >> 6;            // 0..3
    const int wr = wave >> 1;           // wave row 0..1 (64-row slab)
    const int wc = wave & 1;            // wave col 0..1 (64-col slab)

    // T1: XCD swizzle; grid = 5504 = 8*688, bijective.
    int bid = blockIdx.x;
    bid = (bid & 7) * ((M_DIM / BM) * (N_DIM / BN) / 8) + (bid >> 3);

    const int tm = bid / (N_DIM / BN);
    const int tn = bid % (N_DIM / BN);
    const int mBase = tm * BM;
    const int nBase = tn * BN;

    const int cl = lane & 15;           // fragment row/col index
    const int rl = lane >> 4;           // 0..3, k-group

    f32x4 acc[4][4];
    #pragma unroll
    for (int i = 0; i < 4; ++i)
        #pragma unroll
        for (int j = 0; j < 4; ++j)
            acc[i][j] = (f32x4){0.f, 0.f, 0.f, 0.f};

    for (int kt = 0; kt < K_DIM / BK; ++kt) {
        const int kBase = kt * BK;

        // ---- global f32 -> registers (16B float4 loads, coalesced) ----
        // Tile = 128x64 f32; per thread 8 chunks of 4 floats.
        // chunk cc: e = cc*1024 + t*4 ; row = e>>6, col = e&63.
        f32x4 ra[8], rb[8];
        #pragma unroll
        for (int cc = 0; cc < 8; ++cc) {
            const int e = cc * 1024 + t * 4;
            const int r = e >> 6;
            const int c = e & 63;
            ra[cc] = *(const f32x4*)(X + (size_t)(mBase + r) * K_DIM + kBase + c);
            rb[cc] = *(const f32x4*)(W + (size_t)(nBase + r) * K_DIM + kBase + c);
        }

        __syncthreads();   // all waves done reading LDS from previous iter

        // ---- convert f32->bf16 (RNE) and write LDS (b64 writes) ----
        #pragma unroll
        for (int cc = 0; cc < 8; ++cc) {
            const int e = cc * 1024 + t * 4;
            u16x4 pa, pb;
            #pragma unroll
            for (int q = 0; q < 4; ++q) { pa[q] = f2bf(ra[cc][q]); pb[q] = f2bf(rb[cc][q]); }
            *(u16x4*)(smA + e) = pa;
            *(u16x4*)(smB + e) = pb;
        }

        __syncthreads();   // tiles visible

        // ---- LDS -> bf16x8 frags -> MFMA ----
        #pragma unroll
        for (int kk = 0; kk < BK / 32; ++kk) {
            bf16x8 afr[4], bfr[4];
            #pragma unroll
            for (int i = 0; i < 4; ++i) {
                // A-frag: row = wr*64+i*16+(lane&15), k = kk*32+(lane>>4)*8 ..+7
                afr[i] = *(const bf16x8*)(smA + (wr * 64 + i * 16 + cl) * BK + kk * 32 + rl * 8);
                // B-frag (B^T GEMM): W-row = wc*64+i*16+(lane&15), same k slice
                bfr[i] = *(const bf16x8*)(smB + (wc * 64 + i * 16 + cl) * BK + kk * 32 + rl * 8);
            }
            #pragma unroll
            for (int i = 0; i < 4; ++i)
                #pragma unroll
                for (int j = 0; j < 4; ++j)
                    acc[i][j] = __builtin_amdgcn_mfma_f32_16x16x32_bf16(
                        afr[i], bfr[j], acc[i][j], 0, 0, 0);
        }
    }

    // Epilogue: out = acc * sx[row] * sw[col] + bias[col], f32 store.
    // C/D layout: col = lane&15, row = (lane>>4)*4 + reg  (m89/m91 verified)
    float sxv[4][4];
    #pragma unroll
    for (int i = 0; i < 4; ++i) {
        const int gm = mBase + wr * 64 + i * 16 + rl * 4;
        #pragma unroll
        for (int r = 0; r < 4; ++r)
            sxv[i][r] = SX[gm + r];
    }
    #pragma unroll
    for (int j = 0; j < 4; ++j) {
        const int gn = nBase + wc * 64 + j * 16 + cl;
        const float swv = SW[gn];
        const float bv  = BIAS[gn];
        #pragma unroll
        for (int i = 0; i < 4; ++i) {
            const int gmb = mBase + wr * 64 + i * 16 + rl * 4;
            #pragma unroll
            for (int r = 0; r < 4; ++r) {
                float v = acc[i][j][r] * sxv[i][r] * swv + bv;
                // sentinel (no-op when correct, |v| <= ~700):
                // pass ~1-4 | ~696 semantics wrong | ~1e5 garbage persists
                v = fminf(fmaxf(v, -1.0e5f), 1.0e5f);
                OUT[(size_t)(gmb + r) * N_DIM + gn] = v;
            }
        }
    }
}

extern "C" void kernel_launch(void* const* d_in, const int* in_sizes, int n_in,
                              void* d_out, int out_size, void* d_ws, size_t ws_size,
                              hipStream_t stream) {
    // By-size selection for the three unique sizes; dict order for the two
    // N-sized inputs (weight_scales first, bias second).
    const void* pX = d_in[0]; const void* pSX = d_in[1]; const void* pW = d_in[2];
    const void* pSW = d_in[3]; const void* pBS = d_in[4];
    for (int i = 0; i < n_in; ++i) {
        if (in_sizes[i] == M_DIM * K_DIM)      pX  = d_in[i];
        else if (in_sizes[i] == M_DIM)         pSX = d_in[i];
        else if (in_sizes[i] == N_DIM * K_DIM) pW  = d_in[i];
    }
    {
        int first = -1, second = -1;
        for (int i = 0; i < n_in; ++i)
            if (in_sizes[i] == N_DIM) { if (first < 0) first = i; else if (second < 0) second = i; }
        if (first >= 0)  pSW = d_in[first];
        if (second >= 0) pBS = d_in[second];
    }

    dim3 grid((M_DIM / BM) * (N_DIM / BN));   // 64 * 86 = 5504 blocks
    linear_flh_kernel<<<grid, 256, 0, stream>>>(
        (const float*)pX, (const float*)pSX,
        (const float*)pW, (const float*)pSW,
        (const float*)pBS, (float*)d_out);
}

// Round 8
// 1166.213 us; speedup vs baseline: 1.4389x; 1.4389x over previous
//
#include <hip/hip_runtime.h>
#include <hip/hip_bf16.h>

// LinearFLH: out[m,n] = sx[m]*sw[n]*(x[m,:].w[n,:]) + bias[n]
// M=8192, N=11008, K=4096. All harness buffers are FLOAT32 (fp16 ref dtype ->
// harness "else float" rule, established R6/R7).
// R8 structure: (1) elementwise f32->bf16 convert of X and W into d_ws
// (157 MB bf16 -> both operands L3-resident; R7's 6.0 GB FETCH was f32
// panels thrashing the 256 MB L3), (2) m97 128x128/BK=64 bf16 MFMA GEMM
// with global_load_lds(16B) staging (verified 874-912 TF structure; R1/R2's
// NaN was the f32-as-bf16 misread, not this path). Fallback to R7's inline-
// convert GEMM if ws_size is too small (host-side deterministic branch).

#define M_DIM 8192
#define N_DIM 11008
#define K_DIM 4096
#define BM 128
#define BN 128
#define BK 64

#define X_ELEMS (M_DIM * K_DIM)            // 33,554,432
#define W_ELEMS (N_DIM * K_DIM)            // 45,088,768
#define WS_NEEDED ((size_t)(X_ELEMS + W_ELEMS) * 2)   // 157,286,400 B

typedef __bf16 bf16x8 __attribute__((ext_vector_type(8)));   // MFMA A/B operand
typedef float f32x4 __attribute__((ext_vector_type(4)));
typedef unsigned short u16x4 __attribute__((ext_vector_type(4)));
typedef unsigned short u16x8 __attribute__((ext_vector_type(8)));

typedef __attribute__((address_space(3))) void lds_void;
typedef const __attribute__((address_space(1))) void gmem_void;

// f32 -> bf16 bits, round-to-nearest-even (branchless; inputs finite)
__device__ __forceinline__ unsigned short f2bf(float f) {
    union { float f; unsigned int u; } c; c.f = f;
    unsigned int r = c.u + 0x7FFFu + ((c.u >> 16) & 1u);
    return (unsigned short)(r >> 16);
}

// ---------------- elementwise convert: f32 -> bf16 ----------------
__global__ __launch_bounds__(256) void convert_f32_to_bf16(
    const float* __restrict__ in, unsigned short* __restrict__ out, int n)
{
    int idx = (blockIdx.x * 256 + threadIdx.x) * 8;
    const int stride = gridDim.x * 256 * 8;
    for (; idx < n; idx += stride) {
        const f32x4 a = *(const f32x4*)(in + idx);
        const f32x4 b = *(const f32x4*)(in + idx + 4);
        u16x8 o;
        #pragma unroll
        for (int q = 0; q < 4; ++q) { o[q] = f2bf(a[q]); o[q + 4] = f2bf(b[q]); }
        *(u16x8*)(out + idx) = o;
    }
}

// ---------------- main GEMM: bf16 operands via global_load_lds ----------------
__global__ __launch_bounds__(256) void linear_flh_gemm_bf16(
    const unsigned short* __restrict__ Xb,   // [M, K] bf16 bits (ws)
    const unsigned short* __restrict__ Wb,   // [N, K] bf16 bits (ws)
    const float* __restrict__ SX,            // [M] f32
    const float* __restrict__ SW,            // [N] f32
    const float* __restrict__ BIAS,          // [N] f32
    float* __restrict__ OUT)                 // [M, N] f32
{
    __shared__ alignas(16) unsigned short smA[BM * BK];   // 16 KiB
    __shared__ alignas(16) unsigned short smB[BN * BK];   // 16 KiB

    const int t = threadIdx.x;          // 0..255
    const int lane = t & 63;
    const int wave = t >> 6;            // 0..3
    const int wr = wave >> 1;           // wave row 0..1 (64-row slab)
    const int wc = wave & 1;            // wave col 0..1 (64-col slab)

    // T1: XCD swizzle; grid = 5504 = 8*688, bijective.
    int bid = blockIdx.x;
    bid = (bid & 7) * ((M_DIM / BM) * (N_DIM / BN) / 8) + (bid >> 3);

    const int tm = bid / (N_DIM / BN);
    const int tn = bid % (N_DIM / BN);
    const int mBase = tm * BM;
    const int nBase = tn * BN;

    const int cl = lane & 15;           // fragment row/col index
    const int rl = lane >> 4;           // 0..3, k-group

    f32x4 acc[4][4];
    #pragma unroll
    for (int i = 0; i < 4; ++i)
        #pragma unroll
        for (int j = 0; j < 4; ++j)
            acc[i][j] = (f32x4){0.f, 0.f, 0.f, 0.f};

    for (int kt = 0; kt < K_DIM / BK; ++kt) {
        const int kBase = kt * BK;
        // Stage A/B tiles async global->LDS, 16B/lane/issue, 4 issues each.
        // LDS dest is linear in thread id (wave-uniform base + lane*16). (m104)
        #pragma unroll
        for (int it = 0; it < 4; ++it) {
            const int e = it * 2048 + t * 8;   // element offset in 128x64 tile
            const int r = e >> 6;
            const int c = e & 63;
            const unsigned short* ga = Xb + (size_t)(mBase + r) * K_DIM + kBase + c;
            __builtin_amdgcn_global_load_lds((gmem_void*)ga, (lds_void*)(smA + e), 16, 0, 0);
            const unsigned short* gb = Wb + (size_t)(nBase + r) * K_DIM + kBase + c;
            __builtin_amdgcn_global_load_lds((gmem_void*)gb, (lds_void*)(smB + e), 16, 0, 0);
        }
        __syncthreads();   // compiler drains vmcnt(0) before barrier

        #pragma unroll
        for (int kk = 0; kk < BK / 32; ++kk) {
            bf16x8 afr[4], bfr[4];
            #pragma unroll
            for (int i = 0; i < 4; ++i) {
                // A-frag: row = wr*64+i*16+(lane&15), k = kk*32+(lane>>4)*8 ..+7
                afr[i] = *(const bf16x8*)(smA + (wr * 64 + i * 16 + cl) * BK + kk * 32 + rl * 8);
                // B-frag (B^T GEMM): W-row = wc*64+i*16+(lane&15), same k slice
                bfr[i] = *(const bf16x8*)(smB + (wc * 64 + i * 16 + cl) * BK + kk * 32 + rl * 8);
            }
            #pragma unroll
            for (int i = 0; i < 4; ++i)
                #pragma unroll
                for (int j = 0; j < 4; ++j)
                    acc[i][j] = __builtin_amdgcn_mfma_f32_16x16x32_bf16(
                        afr[i], bfr[j], acc[i][j], 0, 0, 0);
        }
        __syncthreads();
    }

    // Epilogue: out = acc * sx[row] * sw[col] + bias[col], f32 store.
    // C/D layout: col = lane&15, row = (lane>>4)*4 + reg  (m89/m91)
    float sxv[4][4];
    #pragma unroll
    for (int i = 0; i < 4; ++i) {
        const int gm = mBase + wr * 64 + i * 16 + rl * 4;
        #pragma unroll
        for (int r = 0; r < 4; ++r) sxv[i][r] = SX[gm + r];
    }
    #pragma unroll
    for (int j = 0; j < 4; ++j) {
        const int gn = nBase + wc * 64 + j * 16 + cl;
        const float swv = SW[gn];
        const float bv  = BIAS[gn];
        #pragma unroll
        for (int i = 0; i < 4; ++i) {
            const int gmb = mBase + wr * 64 + i * 16 + rl * 4;
            #pragma unroll
            for (int r = 0; r < 4; ++r) {
                float v = acc[i][j][r] * sxv[i][r] * swv + bv;
                // sentinel (no-op when correct): ~1e5 flags staging garbage
                v = fminf(fmaxf(v, -1.0e5f), 1.0e5f);
                OUT[(size_t)(gmb + r) * N_DIM + gn] = v;
            }
        }
    }
}

// ---------------- fallback (R7): inline-convert reg-staged GEMM ----------------
__global__ __launch_bounds__(256) void linear_flh_gemm_f32in(
    const float* __restrict__ X, const float* __restrict__ SX,
    const float* __restrict__ W, const float* __restrict__ SW,
    const float* __restrict__ BIAS, float* __restrict__ OUT)
{
    __shared__ alignas(16) unsigned short smA[BM * BK];
    __shared__ alignas(16) unsigned short smB[BN * BK];

    const int t = threadIdx.x;
    const int lane = t & 63;
    const int wave = t >> 6;
    const int wr = wave >> 1;
    const int wc = wave & 1;

    int bid = blockIdx.x;
    bid = (bid & 7) * ((M_DIM / BM) * (N_DIM / BN) / 8) + (bid >> 3);
    const int tm = bid / (N_DIM / BN);
    const int tn = bid % (N_DIM / BN);
    const int mBase = tm * BM;
    const int nBase = tn * BN;
    const int cl = lane & 15;
    const int rl = lane >> 4;

    f32x4 acc[4][4];
    #pragma unroll
    for (int i = 0; i < 4; ++i)
        #pragma unroll
        for (int j = 0; j < 4; ++j) acc[i][j] = (f32x4){0.f, 0.f, 0.f, 0.f};

    for (int kt = 0; kt < K_DIM / BK; ++kt) {
        const int kBase = kt * BK;
        f32x4 ra[8], rb[8];
        #pragma unroll
        for (int cc = 0; cc < 8; ++cc) {
            const int e = cc * 1024 + t * 4;
            const int r = e >> 6;
            const int c = e & 63;
            ra[cc] = *(const f32x4*)(X + (size_t)(mBase + r) * K_DIM + kBase + c);
            rb[cc] = *(const f32x4*)(W + (size_t)(nBase + r) * K_DIM + kBase + c);
        }
        __syncthreads();
        #pragma unroll
        for (int cc = 0; cc < 8; ++cc) {
            const int e = cc * 1024 + t * 4;
            u16x4 pa, pb;
            #pragma unroll
            for (int q = 0; q < 4; ++q) { pa[q] = f2bf(ra[cc][q]); pb[q] = f2bf(rb[cc][q]); }
            *(u16x4*)(smA + e) = pa;
            *(u16x4*)(smB + e) = pb;
        }
        __syncthreads();
        #pragma unroll
        for (int kk = 0; kk < BK / 32; ++kk) {
            bf16x8 afr[4], bfr[4];
            #pragma unroll
            for (int i = 0; i < 4; ++i) {
                afr[i] = *(const bf16x8*)(smA + (wr * 64 + i * 16 + cl) * BK + kk * 32 + rl * 8);
                bfr[i] = *(const bf16x8*)(smB + (wc * 64 + i * 16 + cl) * BK + kk * 32 + rl * 8);
            }
            #pragma unroll
            for (int i = 0; i < 4; ++i)
                #pragma unroll
                for (int j = 0; j < 4; ++j)
                    acc[i][j] = __builtin_amdgcn_mfma_f32_16x16x32_bf16(
                        afr[i], bfr[j], acc[i][j], 0, 0, 0);
        }
    }

    float sxv[4][4];
    #pragma unroll
    for (int i = 0; i < 4; ++i) {
        const int gm = mBase + wr * 64 + i * 16 + rl * 4;
        #pragma unroll
        for (int r = 0; r < 4; ++r) sxv[i][r] = SX[gm + r];
    }
    #pragma unroll
    for (int j = 0; j < 4; ++j) {
        const int gn = nBase + wc * 64 + j * 16 + cl;
        const float swv = SW[gn];
        const float bv  = BIAS[gn];
        #pragma unroll
        for (int i = 0; i < 4; ++i) {
            const int gmb = mBase + wr * 64 + i * 16 + rl * 4;
            #pragma unroll
            for (int r = 0; r < 4; ++r) {
                float v = acc[i][j][r] * sxv[i][r] * swv + bv;
                v = fminf(fmaxf(v, -1.0e5f), 1.0e5f);
                OUT[(size_t)(gmb + r) * N_DIM + gn] = v;
            }
        }
    }
}

extern "C" void kernel_launch(void* const* d_in, const int* in_sizes, int n_in,
                              void* d_out, int out_size, void* d_ws, size_t ws_size,
                              hipStream_t stream) {
    // By-size selection for the three unique sizes; dict order for the two
    // N-sized inputs (weight_scales first, bias second).
    const void* pX = d_in[0]; const void* pSX = d_in[1]; const void* pW = d_in[2];
    const void* pSW = d_in[3]; const void* pBS = d_in[4];
    for (int i = 0; i < n_in; ++i) {
        if (in_sizes[i] == M_DIM * K_DIM)      pX  = d_in[i];
        else if (in_sizes[i] == M_DIM)         pSX = d_in[i];
        else if (in_sizes[i] == N_DIM * K_DIM) pW  = d_in[i];
    }
    {
        int first = -1, second = -1;
        for (int i = 0; i < n_in; ++i)
            if (in_sizes[i] == N_DIM) { if (first < 0) first = i; else if (second < 0) second = i; }
        if (first >= 0)  pSW = d_in[first];
        if (second >= 0) pBS = d_in[second];
    }

    dim3 grid((M_DIM / BM) * (N_DIM / BN));   // 5504 blocks

    if (ws_size >= WS_NEEDED) {
        unsigned short* Xb = (unsigned short*)d_ws;
        unsigned short* Wb = Xb + X_ELEMS;
        convert_f32_to_bf16<<<2048, 256, 0, stream>>>((const float*)pX, Xb, X_ELEMS);
        convert_f32_to_bf16<<<2048, 256, 0, stream>>>((const float*)pW, Wb, W_ELEMS);
        linear_flh_gemm_bf16<<<grid, 256, 0, stream>>>(
            Xb, Wb, (const float*)pSX, (const float*)pSW, (const float*)pBS,
            (float*)d_out);
    } else {
        linear_flh_gemm_f32in<<<grid, 256, 0, stream>>>(
            (const float*)pX, (const float*)pSX, (const float*)pW,
            (const float*)pSW, (const float*)pBS, (float*)d_out);
    }
}

// Round 10
// 779.379 us; speedup vs baseline: 2.1531x; 1.4963x over previous
//
#include <hip/hip_runtime.h>
#include <hip/hip_bf16.h>

// LinearFLH: out[m,n] = sx[m]*sw[n]*(x[m,:].w[n,:]) + bias[n]
// M=8192, N=11008, K=4096. All harness buffers FLOAT32 (fp16 ref -> "else
// float" rule). Pipeline: (1) f32->bf16 convert of X,W into d_ws, (2) 256x256
// BK=64 bf16 MFMA GEMM, 8 waves, double-buffered LDS with ONE __syncthreads
// per K-tile (provably race-free; R9's raw-barrier+counted-vmcnt schedule was
// non-deterministic -> race). T1 XCD swizzle + T2 XOR LDS swizzle + setprio.

#define M_DIM 8192
#define N_DIM 11008
#define K_DIM 4096
#define BM 256
#define BN 256
#define BK 64
#define NT (K_DIM / BK)                       // 64 K-tiles
#define NWG ((M_DIM / BM) * (N_DIM / BN))     // 32*43 = 1376, % 8 == 0

#define X_ELEMS (M_DIM * K_DIM)
#define W_ELEMS (N_DIM * K_DIM)
#define WS_NEEDED ((size_t)(X_ELEMS + W_ELEMS) * 2)

typedef __bf16 bf16x8 __attribute__((ext_vector_type(8)));
typedef float f32x4 __attribute__((ext_vector_type(4)));
typedef unsigned short u16x4 __attribute__((ext_vector_type(4)));
typedef unsigned short u16x8 __attribute__((ext_vector_type(8)));

typedef __attribute__((address_space(3))) void lds_void;
typedef const __attribute__((address_space(1))) void gmem_void;

// f32 -> bf16 bits, round-to-nearest-even (inputs finite)
__device__ __forceinline__ unsigned short f2bf(float f) {
    union { float f; unsigned int u; } c; c.f = f;
    unsigned int r = c.u + 0x7FFFu + ((c.u >> 16) & 1u);
    return (unsigned short)(r >> 16);
}

// ---------------- elementwise convert: f32 -> bf16 (proven R8) ----------------
__global__ __launch_bounds__(256) void convert_f32_to_bf16(
    const float* __restrict__ in, unsigned short* __restrict__ out, int n)
{
    int idx = (blockIdx.x * 256 + threadIdx.x) * 8;
    const int stride = gridDim.x * 256 * 8;
    for (; idx < n; idx += stride) {
        const f32x4 a = *(const f32x4*)(in + idx);
        const f32x4 b = *(const f32x4*)(in + idx + 4);
        u16x8 o;
        #pragma unroll
        for (int q = 0; q < 4; ++q) { o[q] = f2bf(a[q]); o[q + 4] = f2bf(b[q]); }
        *(u16x8*)(out + idx) = o;
    }
}

// ---------------- main GEMM: 256x256 tile, 8 waves, dbuf + 1 barrier/K-tile ----------------
// LDS layout (ushort elems): buf c in [c*32768, c*32768+32768):
//   A tile [256][64] at c*32768, B tile [256][64] at c*32768+16384.
// T2 swizzle (both sides, rule #21): lds[row][col] holds global[row][col ^ ((row&7)<<3)].
__global__ __launch_bounds__(512, 2) void linear_flh_gemm_256(
    const unsigned short* __restrict__ Xb,   // [M,K] bf16 bits (ws)
    const unsigned short* __restrict__ Wb,   // [N,K] bf16 bits (ws)
    const float* __restrict__ SX,            // [M]
    const float* __restrict__ SW,            // [N]
    const float* __restrict__ BIAS,          // [N]
    float* __restrict__ OUT)                 // [M,N] f32
{
    __shared__ unsigned short lds[65536];    // 128 KiB -> 1 workgroup/CU

    const int t    = threadIdx.x;     // 0..511
    const int lane = t & 63;
    const int wid  = t >> 6;          // 0..7
    const int qr   = wid >> 2;        // 0..1: wave-row within 128x128 quadrant
    const int wcol = wid & 3;         // 0..3: wave-col within quadrant
    const int cl   = lane & 15;       // fragment row/col
    const int rl   = lane >> 4;       // 0..3: k-group

    // T1: XCD swizzle (1376 % 8 == 0 -> bijective)
    int bid = blockIdx.x;
    bid = (bid & 7) * (NWG / 8) + (bid >> 3);
    const int mBase = (bid / (N_DIM / BN)) * BM;
    const int nBase = (bid % (N_DIM / BN)) * BN;

    // T2 read-side: element col = (kk*32 + rl*8) ^ ((row&7)<<3); row&7 == cl&7
    // for every fragment row used below -> per-thread constants. colK1 = colK0^32
    // is exact because rl*8 < 32 and the XOR field covers bits 3..5.
    const int colK0 = (rl * 8) ^ ((cl & 7) << 3);
    const int colK1 = colK0 ^ 32;

    f32x4 acc[4][4][2];   // [quadrant][mi][ni] -- all indices compile-time
    #pragma unroll
    for (int q = 0; q < 4; ++q)
        #pragma unroll
        for (int mi = 0; mi < 4; ++mi)
            #pragma unroll
            for (int ni = 0; ni < 2; ++ni)
                acc[q][mi][ni] = (f32x4){0.f, 0.f, 0.f, 0.f};

    // Stage one K-tile (A+B) into buf DST_ from k-column KCOL_.
    // 512 thr x 16B: 4 issues/operand. LDS dest linear (DMA rule, m104);
    // global source column pre-swizzled with the read-side involution.
    #define STAGE_TILE(DST_, KCOL_)                                            \
        { _Pragma("unroll")                                                    \
          for (int it_ = 0; it_ < 4; ++it_) {                                  \
              const int e_ = it_ * 4096 + t * 8;                               \
              const int r_ = e_ >> 6;                                          \
              const int c_ = ((t & 7) * 8) ^ ((r_ & 7) << 3);                  \
              __builtin_amdgcn_global_load_lds(                                \
                  (gmem_void*)(Xb + (size_t)(mBase + r_) * K_DIM + (KCOL_) + c_),\
                  (lds_void*)(lds + (DST_) + e_), 16, 0, 0);                   \
              __builtin_amdgcn_global_load_lds(                                \
                  (gmem_void*)(Wb + (size_t)(nBase + r_) * K_DIM + (KCOL_) + c_),\
                  (lds_void*)(lds + (DST_) + 16384 + e_), 16, 0, 0);           \
          } }

    STAGE_TILE(0, 0);   // prologue: tile 0 -> buf 0

    for (int kt = 0; kt < NT; ++kt) {
        const int cur = kt & 1;
        // __syncthreads drains vmcnt(0)+lgkmcnt(0) then barriers: buf[cur]'s
        // DMA (issued last iter by ALL waves) is landed and visible. Also
        // orders last iter's reads of buf[cur^1] before this iter's overwrite.
        __syncthreads();
        if (kt + 1 < NT) STAGE_TILE((cur ^ 1) * 32768, (kt + 1) * BK);

        const int abase = cur * 32768;
        const int bbase = abase + 16384;
        #pragma unroll
        for (int q = 0; q < 4; ++q) {
            const int mh = q >> 1, nh = q & 1;
            bf16x8 af[4][2], bf[2][2];
            #pragma unroll
            for (int mi = 0; mi < 4; ++mi) {
                const int row = mh * 128 + qr * 64 + mi * 16 + cl;
                af[mi][0] = *(const bf16x8*)(lds + abase + row * 64 + colK0);
                af[mi][1] = *(const bf16x8*)(lds + abase + row * 64 + colK1);
            }
            #pragma unroll
            for (int ni = 0; ni < 2; ++ni) {
                const int row = nh * 128 + wcol * 32 + ni * 16 + cl;
                bf[ni][0] = *(const bf16x8*)(lds + bbase + row * 64 + colK0);
                bf[ni][1] = *(const bf16x8*)(lds + bbase + row * 64 + colK1);
            }
            __builtin_amdgcn_s_setprio(1);
            #pragma unroll
            for (int mi = 0; mi < 4; ++mi)
                #pragma unroll
                for (int ni = 0; ni < 2; ++ni) {
                    acc[q][mi][ni] = __builtin_amdgcn_mfma_f32_16x16x32_bf16(
                        af[mi][0], bf[ni][0], acc[q][mi][ni], 0, 0, 0);
                    acc[q][mi][ni] = __builtin_amdgcn_mfma_f32_16x16x32_bf16(
                        af[mi][1], bf[ni][1], acc[q][mi][ni], 0, 0, 0);
                }
            __builtin_amdgcn_s_setprio(0);
        }
    }
    #undef STAGE_TILE

    // Epilogue: out = acc * sx[row] * sw[col] + bias[col]; NT stores keep the
    // 360 MB f32 output from evicting bf16 operands out of L3.
    // C/D layout: col = lane&15, row = rl*4 + reg (m89/m91).
    #pragma unroll
    for (int q = 0; q < 4; ++q) {
        const int mh = q >> 1, nh = q & 1;
        #pragma unroll
        for (int mi = 0; mi < 4; ++mi) {
            const int rowb = mBase + mh * 128 + qr * 64 + mi * 16 + rl * 4;
            #pragma unroll
            for (int ni = 0; ni < 2; ++ni) {
                const int col = nBase + nh * 128 + wcol * 32 + ni * 16 + cl;
                const float swv = SW[col];
                const float bv  = BIAS[col];
                #pragma unroll
                for (int rr = 0; rr < 4; ++rr) {
                    const int row = rowb + rr;
                    float v = acc[q][mi][ni][rr] * SX[row] * swv + bv;
                    v = fminf(fmaxf(v, -1.0e5f), 1.0e5f);   // diagnostic sentinel
                    __builtin_nontemporal_store(v, OUT + (size_t)row * N_DIM + col);
                }
            }
        }
    }
}

// ---------------- fallback (R7/R8-proven): inline-convert reg-staged 128^2 ----------------
#define FBM 128
#define FBK 64
__global__ __launch_bounds__(256) void linear_flh_gemm_f32in(
    const float* __restrict__ X, const float* __restrict__ SX,
    const float* __restrict__ W, const float* __restrict__ SW,
    const float* __restrict__ BIAS, float* __restrict__ OUT)
{
    __shared__ alignas(16) unsigned short smA[FBM * FBK];
    __shared__ alignas(16) unsigned short smB[FBM * FBK];
    const int t = threadIdx.x;
    const int lane = t & 63, wave = t >> 6;
    const int wr = wave >> 1, wc = wave & 1;
    int bid = blockIdx.x;
    bid = (bid & 7) * ((M_DIM / FBM) * (N_DIM / FBM) / 8) + (bid >> 3);
    const int mBase = (bid / (N_DIM / FBM)) * FBM;
    const int nBase = (bid % (N_DIM / FBM)) * FBM;
    const int cl = lane & 15, rl = lane >> 4;
    f32x4 acc[4][4];
    #pragma unroll
    for (int i = 0; i < 4; ++i)
        #pragma unroll
        for (int j = 0; j < 4; ++j) acc[i][j] = (f32x4){0.f, 0.f, 0.f, 0.f};
    for (int kt = 0; kt < K_DIM / FBK; ++kt) {
        const int kBase = kt * FBK;
        f32x4 ra[8], rb[8];
        #pragma unroll
        for (int cc = 0; cc < 8; ++cc) {
            const int e = cc * 1024 + t * 4;
            const int r = e >> 6, c = e & 63;
            ra[cc] = *(const f32x4*)(X + (size_t)(mBase + r) * K_DIM + kBase + c);
            rb[cc] = *(const f32x4*)(W + (size_t)(nBase + r) * K_DIM + kBase + c);
        }
        __syncthreads();
        #pragma unroll
        for (int cc = 0; cc < 8; ++cc) {
            const int e = cc * 1024 + t * 4;
            u16x4 pa, pb;
            #pragma unroll
            for (int q = 0; q < 4; ++q) { pa[q] = f2bf(ra[cc][q]); pb[q] = f2bf(rb[cc][q]); }
            *(u16x4*)(smA + e) = pa;
            *(u16x4*)(smB + e) = pb;
        }
        __syncthreads();
        #pragma unroll
        for (int kk = 0; kk < FBK / 32; ++kk) {
            bf16x8 afr[4], bfr[4];
            #pragma unroll
            for (int i = 0; i < 4; ++i) {
                afr[i] = *(const bf16x8*)(smA + (wr * 64 + i * 16 + cl) * FBK + kk * 32 + rl * 8);
                bfr[i] = *(const bf16x8*)(smB + (wc * 64 + i * 16 + cl) * FBK + kk * 32 + rl * 8);
            }
            #pragma unroll
            for (int i = 0; i < 4; ++i)
                #pragma unroll
                for (int j = 0; j < 4; ++j)
                    acc[i][j] = __builtin_amdgcn_mfma_f32_16x16x32_bf16(
                        afr[i], bfr[j], acc[i][j], 0, 0, 0);
        }
    }
    #pragma unroll
    for (int j = 0; j < 4; ++j) {
        const int gn = nBase + wc * 64 + j * 16 + cl;
        const float swv = SW[gn], bv = BIAS[gn];
        #pragma unroll
        for (int i = 0; i < 4; ++i) {
            const int gmb = mBase + wr * 64 + i * 16 + rl * 4;
            #pragma unroll
            for (int r = 0; r < 4; ++r) {
                float v = acc[i][j][r] * SX[gmb + r] * swv + bv;
                v = fminf(fmaxf(v, -1.0e5f), 1.0e5f);
                OUT[(size_t)(gmb + r) * N_DIM + gn] = v;
            }
        }
    }
}

extern "C" void kernel_launch(void* const* d_in, const int* in_sizes, int n_in,
                              void* d_out, int out_size, void* d_ws, size_t ws_size,
                              hipStream_t stream) {
    const void* pX = d_in[0]; const void* pSX = d_in[1]; const void* pW = d_in[2];
    const void* pSW = d_in[3]; const void* pBS = d_in[4];
    for (int i = 0; i < n_in; ++i) {
        if (in_sizes[i] == M_DIM * K_DIM)      pX  = d_in[i];
        else if (in_sizes[i] == M_DIM)         pSX = d_in[i];
        else if (in_sizes[i] == N_DIM * K_DIM) pW  = d_in[i];
    }
    {
        int first = -1, second = -1;
        for (int i = 0; i < n_in; ++i)
            if (in_sizes[i] == N_DIM) { if (first < 0) first = i; else if (second < 0) second = i; }
        if (first >= 0)  pSW = d_in[first];
        if (second >= 0) pBS = d_in[second];
    }

    if (ws_size >= WS_NEEDED) {
        unsigned short* Xb = (unsigned short*)d_ws;
        unsigned short* Wb = Xb + X_ELEMS;
        convert_f32_to_bf16<<<2048, 256, 0, stream>>>((const float*)pX, Xb, X_ELEMS);
        convert_f32_to_bf16<<<2048, 256, 0, stream>>>((const float*)pW, Wb, W_ELEMS);
        linear_flh_gemm_256<<<dim3(NWG), 512, 0, stream>>>(
            Xb, Wb, (const float*)pSX, (const float*)pSW, (const float*)pBS,
            (float*)d_out);
    } else {
        dim3 grid((M_DIM / FBM) * (N_DIM / FBM));
        linear_flh_gemm_f32in<<<grid, 256, 0, stream>>>(
            (const float*)pX, (const float*)pSX, (const float*)pW,
            (const float*)pSW, (const float*)pBS, (float*)d_out);
    }
}